// Round 8
// baseline (175.740 us; speedup 1.0000x reference)
//
#include <hip/hip_runtime.h>
#include <math.h>

#define EMBED   64
#define HIDDEN  256
#define SEQ     200
#define SEQP    208          // padded to 13 s-tiles of 16
#define MT      13
#define VOCAB   100000

typedef _Float16 f16x8  __attribute__((ext_vector_type(8)));
typedef _Float16 f16x2  __attribute__((ext_vector_type(2)));
typedef float    f32x4  __attribute__((ext_vector_type(4)));
typedef float    f32x2  __attribute__((ext_vector_type(2)));

// ---------------- ws layout ----------------
// [0   , 32K ) fragW16: f16 (W0+W2)     [tile 16][kc 2][lane 64] x f16x8
// [32K , 64K ) fragW3 : f16 W3          [tile 16][kc 2][lane 64] x f16x8
// [64K , 96K ) fragDt : f16 (W1-W2)^T   [tile 16][kc 2][lane 64] x f16x8
// [96K , 160K) fragB2 : f16 mlp_w1      [tile 16][kc 4][lane 64] x f16x8
// [160K, 160K+12.8M) emb16: f16(user_emb), 128 B/vocab row (L3-resident)
//
// R19: ALL-F16 datapath. fp8 16x16x32 MFMA has the SAME throughput as f16
// 16x16x32 (non-scaled fp8 = bf16 rate), so the fp8 merge bought zero MFMAs
// and cost a per-wave cvt chain + scale bookkeeping. No 16x/256x scaling
// anywhere anymore (also more accurate).
// LESSONS: ws is re-poisoned per launch (no cross-launch caching, R17);
// cross-phase reg state spills at tight bounds (R13/R14); grid-wide
// single-line atomics cost ~100 us (R17).

__global__ void din_setup(const float* __restrict__ attn_w1,
                          const float* __restrict__ mlp_w1,
                          const float* __restrict__ user_emb,
                          _Float16* __restrict__ fragW16,
                          _Float16* __restrict__ fragW3,
                          _Float16* __restrict__ fragDt,
                          _Float16* __restrict__ fragB2,
                          _Float16* __restrict__ emb16,
                          int do_emb) {
  const int gid = blockIdx.x * 256 + threadIdx.x;
  if (gid < 2048) {                                 // fragW16: f16 (W0+W2)
    const int i = gid >> 7, rem = gid & 127, kc = rem >> 6, lane = rem & 63;
    const int n = i * 16 + (lane & 15);
    const int kb = kc * 32 + (lane >> 4) * 8;
    #pragma unroll
    for (int j = 0; j < 8; ++j)
      fragW16[gid * 8 + j] = (_Float16)(attn_w1[(kb + j) * HIDDEN + n]
                                      + attn_w1[(128 + kb + j) * HIDDEN + n]);
  } else if (gid < 4096) {                          // fragW3: f16 W3
    const int g = gid - 2048;
    const int i = g >> 7, rem = g & 127, kc = rem >> 6, lane = rem & 63;
    const int n = i * 16 + (lane & 15);
    const int kb = kc * 32 + (lane >> 4) * 8;
    #pragma unroll
    for (int j = 0; j < 8; ++j)
      fragW3[g * 8 + j] = (_Float16)attn_w1[(192 + kb + j) * HIDDEN + n];
  } else if (gid < 6144) {                          // fragDt: f16 (W1-W2)^T A-frags
    const int g = gid - 4096;
    const int i = g >> 7, rem = g & 127, kc = rem >> 6, lane = rem & 63;
    const int n = i * 16 + (lane & 15);
    const int kb = kc * 32 + (lane >> 4) * 8;
    #pragma unroll
    for (int j = 0; j < 8; ++j)
      fragDt[g * 8 + j] = (_Float16)(attn_w1[(64 + kb + j) * HIDDEN + n]
                                   - attn_w1[(128 + kb + j) * HIDDEN + n]);
  } else if (gid < 10240) {                         // fragB2: mlp_w1 f16 A-frags
    const int g = gid - 6144;
    const int nt = g >> 8, kc = (g >> 6) & 3, lane = g & 63;
    const int n = nt * 16 + (lane & 15);
    const int kb = kc * 32 + (lane >> 4) * 8;
    #pragma unroll
    for (int j = 0; j < 8; ++j)
      fragB2[g * 8 + j] = (_Float16)mlp_w1[(kb + j) * HIDDEN + n];
  } else if (do_emb) {                              // emb16: f16(user_emb)
    const int g = gid - 10240;                      // [0, 800000)
    if (g < VOCAB * EMBED / 8) {
      const int base = g * 8;
      const float4 x = *reinterpret_cast<const float4*>(&user_emb[base]);
      const float4 y = *reinterpret_cast<const float4*>(&user_emb[base + 4]);
      uint4 pv;
      pv.x = __builtin_bit_cast(unsigned, __builtin_amdgcn_cvt_pkrtz(x.x, x.y));
      pv.y = __builtin_bit_cast(unsigned, __builtin_amdgcn_cvt_pkrtz(x.z, x.w));
      pv.z = __builtin_bit_cast(unsigned, __builtin_amdgcn_cvt_pkrtz(y.x, y.y));
      pv.w = __builtin_bit_cast(unsigned, __builtin_amdgcn_cvt_pkrtz(y.z, y.w));
      *reinterpret_cast<uint4*>(&emb16[base]) = pv;
    }
  }
}

// ---------------- fused kernel: one block (256 thr, 4 waves) per row ----------------
// Canary: WRITE_SIZE >= 1 MB => the f16 A-frag live set (~95 regs) spilled.
__global__ __launch_bounds__(256, 4)
void din_fused_kernel(const int* __restrict__ user_hist,
                      const int* __restrict__ target_item,
                      const float* __restrict__ user_emb,
                      const float* __restrict__ item_emb,
                      const float* __restrict__ attn_b1,
                      const float* __restrict__ attn_w2,
                      const float* __restrict__ mlp_b1,
                      const float* __restrict__ mlp_w2,
                      const float* __restrict__ mlp_b2,
                      const _Float16* __restrict__ fragW16,
                      const _Float16* __restrict__ fragW3,
                      const _Float16* __restrict__ fragDt,
                      const _Float16* __restrict__ fragB2,
                      const _Float16* __restrict__ emb16,   // may be null
                      float* __restrict__ out)
{
  __shared__ __align__(16) uint4 Hf16[MT * 2 * 64];       // 26624 B f16 H B-frags
  __shared__ float lp[4][SEQP];                           // 3328 B f32 logit partials
  __shared__ int   histL[SEQP];                           // 832
  __shared__ _Float16 w16s[SEQP];                         // 416, f16 softmax weights
  __shared__ __align__(16) _Float16 t16[EMBED];           // 128
  __shared__ __align__(16) _Float16 mi16[EMBED];          // 128
  __shared__ __align__(16) _Float16 ip16[2 * EMBED];      // 256, pooling partials
  __shared__ float red[8];                                // 32
  // total ~31.7 KB -> 5 blocks/CU LDS-wise

  const int b    = blockIdx.x;
  const int tid  = threadIdx.x;
  const int lane = tid & 63;
  const int wave = tid >> 6;
  const int m    = lane & 15;
  const int quad = lane >> 4;

  // ---- phase 0: target embedding + hist staging ----
  if (tid < EMBED) t16[tid] = (_Float16)item_emb[target_item[b] * EMBED + tid];
  if (tid < SEQP) histL[tid] = (tid < SEQ) ? user_hist[b * SEQ + tid] : 0;
  __syncthreads();

  // ---- phase 1: gather h -> f16 B-frag LDS (16 B/slot) ----
  // slot = tid + 256*i -> st = ((wave>>1)+2i), kc = wave&1, s = s0+32i, kb fixed
  const int s0  = (wave >> 1) * 16 + m;          // 0..31
  const int kb0 = (wave & 1) * 32 + quad * 8;    // 0..56
  if (emb16) {
    #pragma unroll
    for (int i = 0; i < 6; ++i) {                // s <= 191 < SEQ: no predication
      const int s = s0 + 32 * i;
      Hf16[tid + 256 * i] = *reinterpret_cast<const uint4*>(&emb16[histL[s] * EMBED + kb0]);
    }
    {                                            // tail: slots 1536..1663 (wave<2)
      const int s = s0 + 192;
      uint4 pv = uint4{0u, 0u, 0u, 0u};
      if (s < SEQ)
        pv = *reinterpret_cast<const uint4*>(&emb16[histL[s] * EMBED + kb0]);
      if (s < SEQP)
        Hf16[tid + 256 * 6] = pv;
    }
  } else {
    #pragma unroll
    for (int i = 0; i < 7; ++i) {
      const int s = s0 + 32 * i;
      if (s < SEQP) {
        uint4 pv = uint4{0u, 0u, 0u, 0u};
        if (s < SEQ) {
          const float4* src = reinterpret_cast<const float4*>(&user_emb[histL[s] * EMBED + kb0]);
          const float4 x = src[0], y = src[1];
          pv.x = __builtin_bit_cast(unsigned, __builtin_amdgcn_cvt_pkrtz(x.x, x.y));
          pv.y = __builtin_bit_cast(unsigned, __builtin_amdgcn_cvt_pkrtz(x.z, x.w));
          pv.z = __builtin_bit_cast(unsigned, __builtin_amdgcn_cvt_pkrtz(y.x, y.y));
          pv.w = __builtin_bit_cast(unsigned, __builtin_amdgcn_cvt_pkrtz(y.z, y.w));
        }
        Hf16[tid + 256 * i] = pv;
      }
    }
  }

  // ---- phase 2: f16 A-frag merge + c-fold for 4 n-tiles (overlaps gather drain) ----
  f16x8 Aw16[4][2];
  f32x4 cn4[4];
  f32x2 w2n2[4][2];
  {
    const f16x8 tv0 = *reinterpret_cast<const f16x8*>(&t16[quad * 8]);
    const f16x8 tv1 = *reinterpret_cast<const f16x8*>(&t16[32 + quad * 8]);
    #pragma unroll
    for (int i = 0; i < 4; ++i) {
      const int tile = wave * 4 + i;
      // merged A-frags: (W0+W2)[k][n] + W3[k][n]*t[k]  (pure pk_fma_f16)
      #pragma unroll
      for (int c = 0; c < 2; ++c) {
        const f16x8 w16 = reinterpret_cast<const f16x8*>(fragW16)[(tile * 2 + c) * 64 + lane];
        const f16x8 w3v = reinterpret_cast<const f16x8*>(fragW3)[(tile * 2 + c) * 64 + lane];
        Aw16[i][c] = w3v * (c ? tv1 : tv0) + w16;
      }
      // c-fold: c[n] = b1[n] + sum_k t[k] D[k][n]; b1 folded into MFMA C-operand
      const f16x8 d0 = reinterpret_cast<const f16x8*>(fragDt)[(tile * 2 + 0) * 64 + lane];
      const f16x8 d1 = reinterpret_cast<const f16x8*>(fragDt)[(tile * 2 + 1) * 64 + lane];
      const int nb = tile * 16 + quad * 4;
      const float4 b1v = *reinterpret_cast<const float4*>(&attn_b1[nb]);
      const float4 w2v = *reinterpret_cast<const float4*>(&attn_w2[nb]);
      f32x4 acc = {b1v.x, b1v.y, b1v.z, b1v.w};
      acc = __builtin_amdgcn_mfma_f32_16x16x32_f16(d0, tv0, acc, 0, 0, 0);
      acc = __builtin_amdgcn_mfma_f32_16x16x32_f16(d1, tv1, acc, 0, 0, 0);
      cn4[i] = acc;
      w2n2[i][0] = f32x2{w2v.x, w2v.y};
      w2n2[i][1] = f32x2{w2v.z, w2v.w};
    }
  }
  __syncthreads();   // gather complete before Hf16 reads

  // ---- phase 3: single-pass f16 K=64 GEMM over 13 s-tiles, 4 n-tiles/wave ----
  const f32x2 zero2 = {0.f, 0.f};
  #pragma unroll 1
  for (int st = 0; st < MT; ++st) {
    const f16x8 hb0 = *reinterpret_cast<const f16x8*>(&Hf16[(st * 2 + 0) * 64 + lane]);
    const f16x8 hb1 = *reinterpret_cast<const f16x8*>(&Hf16[(st * 2 + 1) * 64 + lane]);
    f32x2 lgp = {0.f, 0.f};
    #pragma unroll
    for (int i = 0; i < 4; ++i) {
      f32x4 acc = __builtin_amdgcn_mfma_f32_16x16x32_f16(Aw16[i][0], hb0, cn4[i], 0, 0, 0);
      acc = __builtin_amdgcn_mfma_f32_16x16x32_f16(Aw16[i][1], hb1, acc, 0, 0, 0);
      f32x2 a0 = {acc[0], acc[1]};
      f32x2 a1 = {acc[2], acc[3]};
      a0 = __builtin_elementwise_max(a0, zero2);      // v_pk_max_f32
      a1 = __builtin_elementwise_max(a1, zero2);
      lgp += a0 * w2n2[i][0];                         // v_pk_fma_f32
      lgp += a1 * w2n2[i][1];
    }
    float lg = lgp[0] + lgp[1];
    lg += __shfl_xor(lg, 16, 64);
    lg += __shfl_xor(lg, 32, 64);
    if (lane < 16) lp[wave][st * 16 + lane] = lg;     // conflict-free
  }
  __syncthreads();

  // ---- phase 4: softmax over SEQ; weights stored f16 ----
  float v = -INFINITY, e = 0.0f;
  if (tid < SEQ)
    v = lp[0][tid] + lp[1][tid] + lp[2][tid] + lp[3][tid];
  {
    float mx = v;
    #pragma unroll
    for (int off = 32; off; off >>= 1) mx = fmaxf(mx, __shfl_xor(mx, off, 64));
    if (lane == 0) red[wave] = mx;
  }
  __syncthreads();
  {
    const float mx = fmaxf(fmaxf(red[0], red[1]), fmaxf(red[2], red[3]));
    e = (tid < SEQ) ? expf(v - mx) : 0.0f;
    float ssum = e;
    #pragma unroll
    for (int off = 32; off; off >>= 1) ssum += __shfl_xor(ssum, off, 64);
    if (lane == 0) red[4 + wave] = ssum;
  }
  __syncthreads();
  {
    const float tot = red[4] + red[5] + red[6] + red[7];
    if (tid < SEQP) w16s[tid] = (_Float16)((tid < SEQ) ? e / tot : 0.0f);
  }
  __syncthreads();

  // ---- phase 5: weighted pooling, packed f16; wave -> (kc = w&1, g2 = w>>1) ----
  {
    const int kc = wave & 1, g2 = wave >> 1;
    const f16x2 hz = {(_Float16)0.f, (_Float16)0.f};
    f16x2 hh[4] = {hz, hz, hz, hz};
    #pragma unroll
    for (int st2 = 0; st2 < 7; ++st2) {
      const int st = g2 + 2 * st2;
      if (st < MT) {
        const unsigned wb = *reinterpret_cast<const unsigned short*>(&w16s[st * 16 + m]);
        const f16x2 wt2 = __builtin_bit_cast(f16x2, wb * 0x10001u);
        const uint4 hu = Hf16[(st * 2 + kc) * 64 + lane];
        hh[0] += __builtin_bit_cast(f16x2, hu.x) * wt2;    // v_pk_fma_f16
        hh[1] += __builtin_bit_cast(f16x2, hu.y) * wt2;
        hh[2] += __builtin_bit_cast(f16x2, hu.z) * wt2;
        hh[3] += __builtin_bit_cast(f16x2, hu.w) * wt2;
      }
    }
    #pragma unroll
    for (int off = 1; off <= 8; off <<= 1) {
      #pragma unroll
      for (int k = 0; k < 4; ++k)
        hh[k] += __builtin_bit_cast(f16x2, __shfl_xor(__builtin_bit_cast(int, hh[k]), off, 64));
    }
    if (m == 0) {
      #pragma unroll
      for (int k = 0; k < 4; ++k)
        *reinterpret_cast<f16x2*>(&ip16[g2 * 64 + kc * 32 + quad * 8 + 2 * k]) = hh[k];
    }
  }
  __syncthreads();
  if (tid < EMBED)
    mi16[tid] = (_Float16)((float)ip16[tid] + (float)ip16[64 + tid]);
  __syncthreads();

  // ---- phase 6: prediction head, f16 MFMA; 4 n-tiles/wave ----
  {
    const f16x8 mb0 = *reinterpret_cast<const f16x8*>(&mi16[quad * 8]);
    const f16x8 mb1 = *reinterpret_cast<const f16x8*>(&mi16[32 + quad * 8]);
    const f16x8 tw0 = *reinterpret_cast<const f16x8*>(&t16[quad * 8]);
    const f16x8 tw1 = *reinterpret_cast<const f16x8*>(&t16[32 + quad * 8]);
    float z = 0.f;
    #pragma unroll
    for (int i = 0; i < 4; ++i) {
      const int tt = wave * 4 + i;
      const f16x8* B2 = reinterpret_cast<const f16x8*>(fragB2) + (tt * 4) * 64 + lane;
      const int nb = tt * 16 + quad * 4;
      const float4 bb = *reinterpret_cast<const float4*>(&mlp_b1[nb]);
      const float4 ww = *reinterpret_cast<const float4*>(&mlp_w2[nb]);
      f32x4 acc = {bb.x, bb.y, bb.z, bb.w};
      acc = __builtin_amdgcn_mfma_f32_16x16x32_f16(B2[0],   mb0, acc, 0, 0, 0);
      acc = __builtin_amdgcn_mfma_f32_16x16x32_f16(B2[64],  mb1, acc, 0, 0, 0);
      acc = __builtin_amdgcn_mfma_f32_16x16x32_f16(B2[128], tw0, acc, 0, 0, 0);
      acc = __builtin_amdgcn_mfma_f32_16x16x32_f16(B2[192], tw1, acc, 0, 0, 0);
      z += fmaxf(acc[0], 0.0f) * ww.x;
      z += fmaxf(acc[1], 0.0f) * ww.y;
      z += fmaxf(acc[2], 0.0f) * ww.z;
      z += fmaxf(acc[3], 0.0f) * ww.w;
    }
    z += __shfl_xor(z, 16, 64);
    z += __shfl_xor(z, 32, 64);
    if (lane == 0) red[wave] = z;
  }
  __syncthreads();
  if (tid == 0) {
    const float zz = red[0] + red[1] + red[2] + red[3] + mlp_b2[0];
    out[b] = 1.0f / (1.0f + expf(-zz));
  }
}

extern "C" void kernel_launch(void* const* d_in, const int* in_sizes, int n_in,
                              void* d_out, int out_size, void* d_ws, size_t ws_size,
                              hipStream_t stream) {
  const int*   user_hist   = (const int*)  d_in[0];
  const int*   target_item = (const int*)  d_in[1];
  const float* user_emb    = (const float*)d_in[2];
  const float* item_emb    = (const float*)d_in[3];
  const float* attn_w1     = (const float*)d_in[4];
  const float* attn_b1     = (const float*)d_in[5];
  const float* attn_w2     = (const float*)d_in[6];
  // d_in[7] = attn_b2: constant shift on logits -> cancels in softmax
  const float* mlp_w1      = (const float*)d_in[8];
  const float* mlp_b1      = (const float*)d_in[9];
  const float* mlp_w2      = (const float*)d_in[10];
  const float* mlp_b2      = (const float*)d_in[11];
  float* out = (float*)d_out;

  _Float16* fragW16 = (_Float16*)d_ws;                       // 32 KB
  _Float16* fragW3  = (_Float16*)((char*)d_ws + 32768);      // 32 KB
  _Float16* fragDt  = (_Float16*)((char*)d_ws + 65536);      // 32 KB
  _Float16* fragB2  = (_Float16*)((char*)d_ws + 98304);      // 64 KB
  const size_t emb16_off   = 163840;
  const size_t emb16_bytes = (size_t)VOCAB * EMBED * 2;      // 12.8 MB
  _Float16* emb16 = nullptr;
  if (ws_size >= emb16_off + emb16_bytes)                    // ws_size call-invariant: capture-safe
    emb16 = (_Float16*)((char*)d_ws + emb16_off);

  const int setup_gids   = 10240 + VOCAB * EMBED / 8;
  const int setup_blocks = (setup_gids + 255) / 256;
  din_setup<<<setup_blocks, 256, 0, stream>>>(
      attn_w1, mlp_w1, user_emb, fragW16, fragW3, fragDt, fragB2,
      emb16 ? emb16 : (_Float16*)d_ws, emb16 ? 1 : 0);

  const int batch = in_sizes[1];
  din_fused_kernel<<<batch, 256, 0, stream>>>(
      user_hist, target_item, user_emb, item_emb,
      attn_b1, attn_w2, mlp_b1, mlp_w2, mlp_b2,
      fragW16, fragW3, fragDt, fragB2, emb16, out);
}